// Round 7
// baseline (238.050 us; speedup 1.0000x reference)
//
#include <hip/hip_runtime.h>
#include <hip/hip_bf16.h>
#include <cstdint>
#include <cstddef>

// B=4, S=2048, D=1024 causal attention head, fp32 in/out.
// R7: sc/pv move to 64x128 tiles (IT=2) -> 2x block parallelism (1088/1024
// blocks), 3-stage distance-2 pipeline everywhere. qv unchanged (R6-best).

using bf16 = __hip_bfloat16;
typedef __attribute__((ext_vector_type(8))) short short8;   // 8 bf16 (A/B frag)
typedef __attribute__((ext_vector_type(4))) float f32x4;    // C/D frag

#define NB 4
#define SS 2048
#define DD 1024

// ---------------------------------------------------------------- async 16B global->LDS
__device__ __forceinline__ void async_lds16(const bf16* g, bf16* l) {
  __builtin_amdgcn_global_load_lds(
      (const __attribute__((address_space(1))) void*)g,
      (__attribute__((address_space(3))) void*)l,
      16, 0, 0);  // HW writes lane i's 16B to ldsbase + i*16
}

struct alignas(8) bf16x4s { bf16 a, b, c, d; };

// ---------------------------------------------------------------- fused prep:
// blocks [0,8192): cvt x -> xb (bf16)
// blocks [8192,8704): transpose qk -> qkT, ov -> ovT (bf16)
// blocks [8704,8712): zero l
__global__ __launch_bounds__(256) void prep_kernel(const float* __restrict__ x,
                                                   bf16* __restrict__ xb,
                                                   const float* __restrict__ qk,
                                                   bf16* __restrict__ qkT,
                                                   const float* __restrict__ ov,
                                                   bf16* __restrict__ ovT,
                                                   float* __restrict__ l) {
  __shared__ bf16 tile[64][65];
  const int bx = blockIdx.x;
  if (bx < 8192) {
    int i = (bx * 256 + threadIdx.x) * 4;
    float4 v = *(const float4*)(x + i);
    bf16x4s o{__float2bfloat16(v.x), __float2bfloat16(v.y),
              __float2bfloat16(v.z), __float2bfloat16(v.w)};
    *(bf16x4s*)(xb + i) = o;
  } else if (bx < 8704) {
    const int idx = bx - 8192;
    const float* in = (idx & 256) ? ov : qk;
    bf16* out = (idx & 256) ? ovT : qkT;
    const int rem = idx & 255;
    const int tbx = (rem & 15) * 64;
    const int tby = (rem >> 4) * 64;
    const int tc = threadIdx.x & 63;
    const int tr = threadIdx.x >> 6;
#pragma unroll
    for (int r = tr; r < 64; r += 4)
      tile[tc][r] = __float2bfloat16(in[(size_t)(tby + r) * DD + tbx + tc]);
    __syncthreads();
#pragma unroll
    for (int r = tr; r < 64; r += 4)
      out[(size_t)(tbx + r) * DD + tby + tc] = tile[r][tc];
  } else {
    const int t = (bx - 8704) * 256 + threadIdx.x;
    f32x4 z = {0.f, 0.f, 0.f, 0.f};
    *(f32x4*)(l + t * 4) = z;
  }
}

// ---------------------------------------------------------------- pipelined NT GEMM core
// C = A[M,K] * Bt[N,K]^T tile at (m0,n0). Tile = (IT*32) x 128, BK=32,
// 4 waves as 2x2; each wave (IT*16) x 64 = IT x 4 mfma 16x16x32 frags.
// Verified operand order (C/D: col=lane&15, row=quad*4+reg) [m89/m91, R1-R6].
// STAGES=3: distance-2 prefetch, raw s_barrier + manual vmcnt.
// Issues/stage: A = IT/2, B = 2 -> vmcnt literals depend on IT.
// EPI: 1 = bf16 store; 2 = exp(acc/32) causal -> bf16 + rowsum atomics; 3 = acc/l[row] f32.
template <int EPI, int STAGES, int IT>
__device__ __forceinline__ void gemm_core(const bf16* __restrict__ Ab,
                                          const bf16* __restrict__ Bb,
                                          void* __restrict__ C,
                                          int N, int K, int m0, int n0, int nk,
                                          bf16* As, bf16* Bs,
                                          float* __restrict__ l) {
  const int tid  = threadIdx.x;
  const int lane = tid & 63;
  const int wave = tid >> 6;
  const int wm   = (wave >> 1) * (IT * 16);
  const int wn   = (wave & 1) << 6;
  const int quad = lane >> 4;
  const int r    = lane & 15;
  const int ASZ  = IT * 1024;  // bf16 per A stage

  f32x4 zero = {0.f, 0.f, 0.f, 0.f};
  f32x4 acc[IT][4];
#pragma unroll
  for (int i = 0; i < IT; ++i)
#pragma unroll
    for (int j = 0; j < 4; ++j) acc[i][j] = zero;

  const long long aoff = (long long)(m0 + (tid >> 2)) * K + (tid & 3) * 8;
  const long long boff = (long long)(n0 + (tid >> 2)) * K + (tid & 3) * 8;

  auto stage = [&](int kt, int s) {
    const long long k0 = (long long)kt << 5;
    bf16* lA = As + s * ASZ + wave * 512;
    bf16* lB = Bs + s * 4096 + wave * 512;
    async_lds16(Ab + aoff + k0, lA);
    if (IT == 4) async_lds16(Ab + aoff + 64LL * K + k0, lA + 2048);
    async_lds16(Bb + boff + k0, lB);
    async_lds16(Bb + boff + 64LL * K + k0, lB + 2048);
  };

  stage(0, 0);
  if (STAGES == 3 && nk > 1) stage(1, 1);

  int s = 0;
  for (int kt = 0; kt < nk; ++kt) {
    if constexpr (STAGES == 3) {
      if (kt + 2 < nk) {
        int s2 = s + 2; if (s2 >= 3) s2 -= 3;
        stage(kt + 2, s2);
        if constexpr (IT == 4) asm volatile("s_waitcnt vmcnt(8)" ::: "memory");
        else                   asm volatile("s_waitcnt vmcnt(6)" ::: "memory");
      } else if (kt + 1 < nk) {
        if constexpr (IT == 4) asm volatile("s_waitcnt vmcnt(4)" ::: "memory");
        else                   asm volatile("s_waitcnt vmcnt(3)" ::: "memory");
      } else {
        asm volatile("s_waitcnt vmcnt(0)" ::: "memory");
      }
    } else {
      if (kt + 1 < nk) {
        stage(kt + 1, s ^ 1);
        if constexpr (IT == 4) asm volatile("s_waitcnt vmcnt(4)" ::: "memory");
        else                   asm volatile("s_waitcnt vmcnt(3)" ::: "memory");
      } else {
        asm volatile("s_waitcnt vmcnt(0)" ::: "memory");
      }
    }
    asm volatile("s_barrier" ::: "memory");

    const bf16* Ak = As + s * ASZ;
    const bf16* Bk = Bs + s * 4096;
    short8 af[IT], bfr[4];
#pragma unroll
    for (int i = 0; i < IT; ++i)
      af[i] = *(const short8*)(Ak + (wm + i * 16 + r) * 32 + quad * 8);
#pragma unroll
    for (int j = 0; j < 4; ++j)
      bfr[j] = *(const short8*)(Bk + (wn + j * 16 + r) * 32 + quad * 8);
#pragma unroll
    for (int i = 0; i < IT; ++i)
#pragma unroll
      for (int j = 0; j < 4; ++j)
        acc[i][j] = __builtin_amdgcn_mfma_f32_16x16x32_bf16(af[i], bfr[j], acc[i][j], 0, 0, 0);

    asm volatile("s_barrier" ::: "memory");
    if constexpr (STAGES == 3) { if (++s == 3) s = 0; } else { s ^= 1; }
  }

  // epilogue: C/D layout col = lane&15, row = quad*4 + reg  [m89/m91, verified R1-R6]
#pragma unroll
  for (int i = 0; i < IT; ++i) {
    const int row0 = m0 + wm + i * 16 + quad * 4;
    if (EPI == 1) {
#pragma unroll
      for (int j = 0; j < 4; ++j) {
        const int col = n0 + wn + j * 16 + r;
#pragma unroll
        for (int q = 0; q < 4; ++q)
          ((bf16*)C)[(long long)(row0 + q) * N + col] = __float2bfloat16(acc[i][j][q]);
      }
    } else if (EPI == 2) {
      float qs[4] = {0.f, 0.f, 0.f, 0.f};
#pragma unroll
      for (int j = 0; j < 4; ++j) {
        const int col = n0 + wn + j * 16 + r;
#pragma unroll
        for (int q = 0; q < 4; ++q) {
          const int row = row0 + q;
          float v = (col <= row) ? __expf(acc[i][j][q] * 0.03125f) : 0.0f;
          ((bf16*)C)[(long long)row * N + col] = __float2bfloat16(v);
          qs[q] += v;
        }
      }
#pragma unroll
      for (int q = 0; q < 4; ++q) {
#pragma unroll
        for (int off = 1; off < 16; off <<= 1) qs[q] += __shfl_xor(qs[q], off, 64);
        if (r == 0) atomicAdd(&l[row0 + q], qs[q]);
      }
    } else {  // EPI == 3
      float rs[4];
#pragma unroll
      for (int q = 0; q < 4; ++q) rs[q] = 1.0f / l[row0 + q];
#pragma unroll
      for (int j = 0; j < 4; ++j) {
        const int col = n0 + wn + j * 16 + r;
#pragma unroll
        for (int q = 0; q < 4; ++q)
          ((float*)C)[(long long)(row0 + q) * N + col] = acc[i][j][q] * rs[q];
      }
    }
  }
}

// ---------------------------------------------------------------- merged Q + V GEMM (unchanged R6-best)
__global__ __launch_bounds__(256) void gemm_qv(const bf16* __restrict__ xb,
                                               const bf16* __restrict__ qkT,
                                               const bf16* __restrict__ ovT,
                                               bf16* __restrict__ Qb,
                                               bf16* __restrict__ Vt) {
  __shared__ bf16 As[3 * 4096];
  __shared__ bf16 Bs[3 * 4096];
  const long long SD = (long long)SS * DD;
  const int z = blockIdx.z;
  if (z < 4) {
    const int by = blockIdx.x & 15, bx = blockIdx.x >> 4;
    gemm_core<1, 3, 4>(xb + z * SD, qkT, Qb + z * SD, DD, DD, by * 128, bx * 128, 32, As, Bs, nullptr);
  } else {
    const int bx = blockIdx.x & 15, by = blockIdx.x >> 4;
    gemm_core<1, 3, 4>(ovT, xb + (z - 4) * SD, Vt + (z - 4) * SD, SS, DD, by * 128, bx * 128, 32, As, Bs, nullptr);
  }
}

// ---------------------------------------------------------------- scores GEMM, 64-row bands
// grid (272, 1, 4). Band bm64 has (bm64>>1)+1 col-tiles:
// offsets: band 2p starts at p(p+1), band 2p+1 at (p+1)^2.
__global__ __launch_bounds__(256) void gemm_sc(const bf16* __restrict__ Qb,
                                               const bf16* __restrict__ xb,
                                               bf16* __restrict__ P,
                                               float* __restrict__ l) {
  __shared__ bf16 As[3 * 2048];
  __shared__ bf16 Bs[3 * 4096];
  const long long SD = (long long)SS * DD;
  const long long SSQ = (long long)SS * SS;
  const int t = blockIdx.x;
  int p = (int)sqrtf((float)t);
  while (p * (p + 1) > t) --p;
  while ((p + 1) * (p + 2) <= t) ++p;
  int bm, bn;
  if (t < (p + 1) * (p + 1)) { bm = 2 * p;     bn = t - p * (p + 1); }
  else                       { bm = 2 * p + 1; bn = t - (p + 1) * (p + 1); }
  const int b = blockIdx.z;
  gemm_core<2, 3, 2>(Qb + b * SD, xb + b * SD, P + b * SSQ, SS, DD, bm * 64, bn * 128, 32,
                     As, Bs, l + b * SS);
}

// ---------------------------------------------------------------- PV GEMM, 64-row bands
// grid (8, 32, 4): bm = 31 - y (longest K first), kEnd = ((m0>>7)+1)*128.
__global__ __launch_bounds__(256) void gemm_pv(const bf16* __restrict__ P,
                                               const bf16* __restrict__ Vt,
                                               const float* __restrict__ l,
                                               float* __restrict__ out) {
  __shared__ bf16 As[3 * 2048];
  __shared__ bf16 Bs[3 * 4096];
  const long long SD = (long long)SS * DD;
  const long long SSQ = (long long)SS * SS;
  const int bm = 31 - blockIdx.y;
  const int m0 = bm * 64;
  const int nk = ((m0 >> 7) + 1) * 4;
  const int b = blockIdx.z;
  gemm_core<3, 3, 2>(P + b * SSQ, Vt + b * SD, out + b * SD, DD, SS, m0, blockIdx.x * 128, nk,
                     As, Bs, (float*)l + b * SS);
}

// ---------------------------------------------------------------- launch
extern "C" void kernel_launch(void* const* d_in, const int* in_sizes, int n_in,
                              void* d_out, int out_size, void* d_ws, size_t ws_size,
                              hipStream_t stream) {
  const float* x  = (const float*)d_in[0];  // [4,2048,1024]
  const float* qk = (const float*)d_in[1];  // [1024,1024]
  const float* ov = (const float*)d_in[2];  // [1024,1024]
  float* out = (float*)d_out;               // [4,2048,1024] fp32

  char* ws = (char*)d_ws;
  const size_t MB = 1ull << 20;
  bf16*  xb  = (bf16*)(ws + 0);          // 16 MB
  bf16*  qkT = (bf16*)(ws + 16 * MB);    //  2 MB
  bf16*  ovT = (bf16*)(ws + 18 * MB);    //  2 MB
  bf16*  Qb  = (bf16*)(ws + 20 * MB);    // 16 MB
  bf16*  Vt  = (bf16*)(ws + 36 * MB);    // 16 MB  V^T per batch [D, S]
  bf16*  P   = (bf16*)(ws + 52 * MB);    // 32 MB  P' = exp(s/32) bf16
  float* l   = (float*)(ws + 84 * MB);   // 32 KB  row sums [B][S]

  prep_kernel<<<dim3(8712), 256, 0, stream>>>(x, xb, qk, qkT, ov, ovT, l);
  gemm_qv<<<dim3(128, 1, 8), 256, 0, stream>>>(xb, qkT, ovT, Qb, Vt);
  gemm_sc<<<dim3(272, 1, 4), 256, 0, stream>>>(Qb, xb, P, l);
  gemm_pv<<<dim3(8, 32, 4), 256, 0, stream>>>(P, Vt, l, out);
}

// Round 9
// 230.272 us; speedup vs baseline: 1.0338x; 1.0338x over previous
//
#include <hip/hip_runtime.h>
#include <hip/hip_cooperative_groups.h>
#include <hip/hip_bf16.h>
#include <cstdint>
#include <cstddef>

// B=4, S=2048, D=1024 causal attention head, fp32 in/out.
// R9: cooperative megakernel, conservative occupancy (32KB LDS 2-stage, grid
// 1024 = 4/CU, launch_bounds(256,4)), occupancy pre-check + return-code check,
// fallback to the R6-verified 4-dispatch path on any launch failure.

namespace cg = cooperative_groups;

using bf16 = __hip_bfloat16;
typedef __attribute__((ext_vector_type(8))) short short8;   // 8 bf16 (A/B frag)
typedef __attribute__((ext_vector_type(4))) float f32x4;    // C/D frag

#define NB 4
#define SS 2048
#define DD 1024
#define MEGA_GRID 1024

// ---------------------------------------------------------------- async 16B global->LDS
__device__ __forceinline__ void async_lds16(const bf16* g, bf16* l) {
  __builtin_amdgcn_global_load_lds(
      (const __attribute__((address_space(1))) void*)g,
      (__attribute__((address_space(3))) void*)l,
      16, 0, 0);  // HW writes lane i's 16B to ldsbase + i*16
}

struct alignas(8) bf16x4s { bf16 a, b, c, d; };

// ---------------------------------------------------------------- pipelined NT GEMM core
// C = A[M,K] * Bt[N,K]^T tile at (m0,n0). 128x128 tile, BK=32, 4 waves x (4x4)
// mfma 16x16x32, verified operand order (C/D: col=lane&15, row=quad*4+reg).
// STAGES=3: distance-2 prefetch (fallback qv). STAGES=2: distance-1.
// Raw s_barrier + manual vmcnt keeps prefetch in flight across barriers.
// EPI: 1 = bf16 store; 2 = exp(acc/32) causal -> bf16 + rowsum atomics; 3 = acc/l[row] f32.
template <int EPI, int STAGES>
__device__ __forceinline__ void gemm_core(const bf16* __restrict__ Ab,
                                          const bf16* __restrict__ Bb,
                                          void* __restrict__ C,
                                          int N, int K, int m0, int n0, int nk,
                                          bf16* As, bf16* Bs,
                                          float* __restrict__ l) {
  const int tid  = threadIdx.x;
  const int lane = tid & 63;
  const int wave = tid >> 6;
  const int wm   = (wave >> 1) << 6;
  const int wn   = (wave & 1) << 6;
  const int quad = lane >> 4;
  const int r    = lane & 15;

  f32x4 zero = {0.f, 0.f, 0.f, 0.f};
  f32x4 acc[4][4];
#pragma unroll
  for (int i = 0; i < 4; ++i)
#pragma unroll
    for (int j = 0; j < 4; ++j) acc[i][j] = zero;

  const long long aoff = (long long)(m0 + (tid >> 2)) * K + (tid & 3) * 8;
  const long long boff = (long long)(n0 + (tid >> 2)) * K + (tid & 3) * 8;

  auto stage = [&](int kt, int s) {
    const long long k0 = (long long)kt << 5;
    bf16* lA = As + s * 4096 + wave * 512;
    bf16* lB = Bs + s * 4096 + wave * 512;
    async_lds16(Ab + aoff + k0, lA);
    async_lds16(Ab + aoff + 64LL * K + k0, lA + 2048);
    async_lds16(Bb + boff + k0, lB);
    async_lds16(Bb + boff + 64LL * K + k0, lB + 2048);
  };

  stage(0, 0);
  if (STAGES == 3 && nk > 1) stage(1, 1);

  int s = 0;
  for (int kt = 0; kt < nk; ++kt) {
    if constexpr (STAGES == 3) {
      if (kt + 2 < nk) {
        int s2 = s + 2; if (s2 >= 3) s2 -= 3;
        stage(kt + 2, s2);
        asm volatile("s_waitcnt vmcnt(8)" ::: "memory");
      } else if (kt + 1 < nk) {
        asm volatile("s_waitcnt vmcnt(4)" ::: "memory");
      } else {
        asm volatile("s_waitcnt vmcnt(0)" ::: "memory");
      }
    } else {
      if (kt + 1 < nk) {
        stage(kt + 1, s ^ 1);
        asm volatile("s_waitcnt vmcnt(4)" ::: "memory");
      } else {
        asm volatile("s_waitcnt vmcnt(0)" ::: "memory");
      }
    }
    asm volatile("s_barrier" ::: "memory");

    const bf16* Ak = As + s * 4096;
    const bf16* Bk = Bs + s * 4096;
    short8 af[4], bfr[4];
#pragma unroll
    for (int i = 0; i < 4; ++i)
      af[i] = *(const short8*)(Ak + (wm + i * 16 + r) * 32 + quad * 8);
#pragma unroll
    for (int j = 0; j < 4; ++j)
      bfr[j] = *(const short8*)(Bk + (wn + j * 16 + r) * 32 + quad * 8);
#pragma unroll
    for (int i = 0; i < 4; ++i)
#pragma unroll
      for (int j = 0; j < 4; ++j)
        acc[i][j] = __builtin_amdgcn_mfma_f32_16x16x32_bf16(af[i], bfr[j], acc[i][j], 0, 0, 0);

    asm volatile("s_barrier" ::: "memory");
    if constexpr (STAGES == 3) { if (++s == 3) s = 0; } else { s ^= 1; }
  }

  // epilogue: C/D layout col = lane&15, row = quad*4 + reg  [m89/m91, verified R1-R7]
#pragma unroll
  for (int i = 0; i < 4; ++i) {
    const int row0 = m0 + wm + i * 16 + quad * 4;
    if (EPI == 1) {
#pragma unroll
      for (int j = 0; j < 4; ++j) {
        const int col = n0 + wn + j * 16 + r;
#pragma unroll
        for (int q = 0; q < 4; ++q)
          ((bf16*)C)[(long long)(row0 + q) * N + col] = __float2bfloat16(acc[i][j][q]);
      }
    } else if (EPI == 2) {
      float qs[4] = {0.f, 0.f, 0.f, 0.f};
#pragma unroll
      for (int j = 0; j < 4; ++j) {
        const int col = n0 + wn + j * 16 + r;
#pragma unroll
        for (int q = 0; q < 4; ++q) {
          const int row = row0 + q;
          float v = (col <= row) ? __expf(acc[i][j][q] * 0.03125f) : 0.0f;
          ((bf16*)C)[(long long)row * N + col] = __float2bfloat16(v);
          qs[q] += v;
        }
      }
#pragma unroll
      for (int q = 0; q < 4; ++q) {
#pragma unroll
        for (int off = 1; off < 16; off <<= 1) qs[q] += __shfl_xor(qs[q], off, 64);
        if (r == 0) atomicAdd(&l[row0 + q], qs[q]);
      }
    } else {  // EPI == 3
      float rs[4];
#pragma unroll
      for (int q = 0; q < 4; ++q) rs[q] = 1.0f / l[row0 + q];
#pragma unroll
      for (int j = 0; j < 4; ++j) {
        const int col = n0 + wn + j * 16 + r;
#pragma unroll
        for (int q = 0; q < 4; ++q)
          ((float*)C)[(long long)(row0 + q) * N + col] = acc[i][j][q] * rs[q];
      }
    }
  }
}

// ---------------------------------------------------------------- shared job bodies
__device__ __forceinline__ void prep_job(int job, const float* x, bf16* xb,
                                         const float* qk, bf16* qkT,
                                         const float* ov, bf16* ovT,
                                         float* l, bf16* smem) {
  if (job < 8192) {
    int i = (job * 256 + (int)threadIdx.x) * 4;
    float4 v = *(const float4*)(x + i);
    bf16x4s o{__float2bfloat16(v.x), __float2bfloat16(v.y),
              __float2bfloat16(v.z), __float2bfloat16(v.w)};
    *(bf16x4s*)(xb + i) = o;
  } else if (job < 8704) {
    bf16 (*tile)[65] = (bf16(*)[65])smem;  // 8.3KB overlay
    const int idx = job - 8192;
    const float* in = (idx & 256) ? ov : qk;
    bf16* outp = (idx & 256) ? ovT : qkT;
    const int rem = idx & 255;
    const int tbx = (rem & 15) * 64;
    const int tby = (rem >> 4) * 64;
    const int tc = threadIdx.x & 63;
    const int tr = threadIdx.x >> 6;
#pragma unroll
    for (int r = tr; r < 64; r += 4)
      tile[tc][r] = __float2bfloat16(in[(size_t)(tby + r) * DD + tbx + tc]);
    __syncthreads();
#pragma unroll
    for (int r = tr; r < 64; r += 4)
      outp[(size_t)(tbx + r) * DD + tby + tc] = tile[r][tc];
    __syncthreads();
  } else {
    const int t = (job - 8704) * 256 + (int)threadIdx.x;
    f32x4 z = {0.f, 0.f, 0.f, 0.f};
    *(f32x4*)(l + t * 4) = z;
  }
}

// ---------------------------------------------------------------- megakernel (32KB LDS, 2-stage)
__global__ __launch_bounds__(256, 4) void mega_kernel(
    const float* __restrict__ x,  bf16* __restrict__ xb,
    const float* __restrict__ qk, bf16* __restrict__ qkT,
    const float* __restrict__ ov, bf16* __restrict__ ovT,
    float* __restrict__ l,
    bf16* __restrict__ Qb, bf16* __restrict__ Vt,
    bf16* __restrict__ P,  float* __restrict__ out) {
  cg::grid_group grid = cg::this_grid();

  __shared__ bf16 smem[4 * 4096];  // 32KB: 2-stage A + 2-stage B
  bf16* As = smem;
  bf16* Bs = smem + 2 * 4096;

  const long long SD = (long long)SS * DD;
  const long long SSQ = (long long)SS * SS;

  // phase 0: prep
  for (int job = blockIdx.x; job < 8712; job += MEGA_GRID)
    prep_job(job, x, xb, qk, qkT, ov, ovT, l, smem);
  grid.sync();

  // phase 1: qv (1024 jobs = exactly 1/block)
  {
    const int job = blockIdx.x;
    const int z = job >> 7;
    const int xj = job & 127;
    if (z < 4) {
      const int by = xj & 15, bx = xj >> 4;
      gemm_core<1, 2>(xb + z * SD, qkT, Qb + z * SD, DD, DD, by * 128, bx * 128, 32, As, Bs, nullptr);
    } else {
      const int bx = xj & 15, by = xj >> 4;
      gemm_core<1, 2>(ovT, xb + (z - 4) * SD, Vt + (z - 4) * SD, SS, DD, by * 128, bx * 128, 32, As, Bs, nullptr);
    }
  }
  grid.sync();

  // phase 2: sc (544 jobs, single round)
  if (blockIdx.x < 544) {
    const int job = blockIdx.x;
    const int b = job / 136;
    const int t = job - b * 136;
    int bm = (int)((sqrtf(8.0f * (float)t + 1.0f) - 1.0f) * 0.5f);
    while ((bm + 1) * (bm + 2) / 2 <= t) ++bm;
    while (bm * (bm + 1) / 2 > t) --bm;
    const int bn = t - bm * (bm + 1) / 2;
    gemm_core<2, 2>(Qb + b * SD, xb + b * SD, P + b * SSQ, SS, DD, bm * 128, bn * 128, 32,
                    As, Bs, l + b * SS);
  }
  grid.sync();

  // phase 3: pv (512 jobs, single round)
  if (blockIdx.x < 512) {
    const int job = blockIdx.x;
    const int bx = job & 7;
    const int by = (job >> 3) & 15;
    const int b = job >> 7;
    const int bm = 15 - by;
    const int m0 = bm * 128;
    const int nk = (m0 + 128) >> 5;
    gemm_core<3, 2>(P + b * SSQ, Vt + b * SD, out + b * SD, DD, SS, m0, bx * 128, nk,
                    As, Bs, (float*)l + b * SS);
  }
}

// ---------------------------------------------------------------- fallback kernels (R6-verified)
__global__ __launch_bounds__(256) void prep_kernel(const float* __restrict__ x,
                                                   bf16* __restrict__ xb,
                                                   const float* __restrict__ qk,
                                                   bf16* __restrict__ qkT,
                                                   const float* __restrict__ ov,
                                                   bf16* __restrict__ ovT,
                                                   float* __restrict__ l) {
  __shared__ bf16 smem[64 * 66];
  prep_job(blockIdx.x, x, xb, qk, qkT, ov, ovT, l, smem);
}

__global__ __launch_bounds__(256) void gemm_qv(const bf16* __restrict__ xb,
                                               const bf16* __restrict__ qkT,
                                               const bf16* __restrict__ ovT,
                                               bf16* __restrict__ Qb,
                                               bf16* __restrict__ Vt) {
  __shared__ bf16 As[3 * 4096];
  __shared__ bf16 Bs[3 * 4096];
  const long long SD = (long long)SS * DD;
  const int z = blockIdx.z;
  if (z < 4) {
    const int by = blockIdx.x & 15, bx = blockIdx.x >> 4;
    gemm_core<1, 3>(xb + z * SD, qkT, Qb + z * SD, DD, DD, by * 128, bx * 128, 32, As, Bs, nullptr);
  } else {
    const int bx = blockIdx.x & 15, by = blockIdx.x >> 4;
    gemm_core<1, 3>(ovT, xb + (z - 4) * SD, Vt + (z - 4) * SD, SS, DD, by * 128, bx * 128, 32, As, Bs, nullptr);
  }
}

__global__ __launch_bounds__(256) void gemm_sc(const bf16* __restrict__ Qb,
                                               const bf16* __restrict__ xb,
                                               bf16* __restrict__ P,
                                               float* __restrict__ l) {
  __shared__ bf16 As[2 * 4096];
  __shared__ bf16 Bs[2 * 4096];
  const long long SD = (long long)SS * DD;
  const long long SSQ = (long long)SS * SS;
  const int t = blockIdx.x;
  int bm = (int)((sqrtf(8.0f * (float)t + 1.0f) - 1.0f) * 0.5f);
  while ((bm + 1) * (bm + 2) / 2 <= t) ++bm;
  while (bm * (bm + 1) / 2 > t) --bm;
  const int bn = t - bm * (bm + 1) / 2;
  const int b = blockIdx.z;
  gemm_core<2, 2>(Qb + b * SD, xb + b * SD, P + b * SSQ, SS, DD, bm * 128, bn * 128, 32,
                  As, Bs, l + b * SS);
}

__global__ __launch_bounds__(256) void gemm_pv(const bf16* __restrict__ P,
                                               const bf16* __restrict__ Vt,
                                               const float* __restrict__ l,
                                               float* __restrict__ out) {
  __shared__ bf16 As[2 * 4096];
  __shared__ bf16 Bs[2 * 4096];
  const long long SD = (long long)SS * DD;
  const long long SSQ = (long long)SS * SS;
  const int bm = 15 - blockIdx.y;
  const int m0 = bm * 128;
  const int nk = (m0 + 128) >> 5;
  const int b = blockIdx.z;
  gemm_core<3, 2>(P + b * SSQ, Vt + b * SD, out + b * SD, DD, SS, m0, blockIdx.x * 128, nk,
                  As, Bs, (float*)l + b * SS);
}

// ---------------------------------------------------------------- launch
extern "C" void kernel_launch(void* const* d_in, const int* in_sizes, int n_in,
                              void* d_out, int out_size, void* d_ws, size_t ws_size,
                              hipStream_t stream) {
  const float* x  = (const float*)d_in[0];  // [4,2048,1024]
  const float* qk = (const float*)d_in[1];  // [1024,1024]
  const float* ov = (const float*)d_in[2];  // [1024,1024]
  float* out = (float*)d_out;               // [4,2048,1024] fp32

  char* ws = (char*)d_ws;
  const size_t MB = 1ull << 20;
  bf16*  xb  = (bf16*)(ws + 0);          // 16 MB
  bf16*  qkT = (bf16*)(ws + 16 * MB);    //  2 MB
  bf16*  ovT = (bf16*)(ws + 18 * MB);    //  2 MB
  bf16*  Qb  = (bf16*)(ws + 20 * MB);    // 16 MB
  bf16*  Vt  = (bf16*)(ws + 36 * MB);    // 16 MB  V^T per batch [D, S]
  bf16*  P   = (bf16*)(ws + 52 * MB);    // 32 MB  P' = exp(s/32) bf16
  float* l   = (float*)(ws + 84 * MB);   // 32 KB  row sums [B][S]

  // capture-safe occupancy pre-check: coop launch only if >= 4 blocks/CU fit
  int occ = 0;
  hipError_t qerr = hipOccupancyMaxActiveBlocksPerMultiprocessor(
      &occ, (const void*)mega_kernel, 256, 0);
  bool coop_ok = (qerr == hipSuccess && occ >= 4);

  if (coop_ok) {
    void* args[] = {(void*)&x, (void*)&xb, (void*)&qk, (void*)&qkT,
                    (void*)&ov, (void*)&ovT, (void*)&l,
                    (void*)&Qb, (void*)&Vt, (void*)&P, (void*)&out};
    hipError_t lerr = hipLaunchCooperativeKernel((const void*)mega_kernel,
                                                 dim3(MEGA_GRID), dim3(256),
                                                 args, 0, stream);
    if (lerr == hipSuccess) return;
  }

  // fallback: R6-verified 4-dispatch path
  prep_kernel<<<dim3(8712), 256, 0, stream>>>(x, xb, qk, qkT, ov, ovT, l);
  gemm_qv<<<dim3(128, 1, 8), 256, 0, stream>>>(xb, qkT, ovT, Qb, Vt);
  gemm_sc<<<dim3(136, 1, 4), 256, 0, stream>>>(Qb, xb, P, l);
  gemm_pv<<<dim3(8, 16, 4), 256, 0, stream>>>(P, Vt, l, out);
}